// Round 6
// baseline (116.422 us; speedup 1.0000x reference)
//
#include <hip/hip_runtime.h>
#include <cstdint>
#include <cstddef>

typedef unsigned short u16;
typedef __attribute__((ext_vector_type(8))) short short8;
typedef __attribute__((ext_vector_type(8))) unsigned short u16x8;
typedef __attribute__((ext_vector_type(4))) float f32x4;

#define NB   96
#define TO   50
#define TW   40
#define DD   512
#define MROWS (NB*TW)      /* 3840 */
#define BM   128
#define BK   32
#define NKC  (DD/BK)       /* 16 */

/* workspace layout (bytes) */
#define WBF_OFF   0u
#define OBF_OFF   (MROWS*DD*2u)              /* 3,932,160  */
#define LOG_OFF   (OBF_OFF + NB*TO*DD*2u)    /* 8,847,360  */
#define ZB_OFF    (LOG_OFF + MROWS*NB*4u)    /* 10,321,920 */

__device__ __forceinline__ u16 f2bf(float f) {
  unsigned int u = __builtin_bit_cast(unsigned int, f);
  u += 0x7fffu + ((u >> 16) & 1u);           /* RNE */
  return (u16)(u >> 16);
}

__device__ __forceinline__ void gload16(const void* g, void* l) {
  __builtin_amdgcn_global_load_lds(
      (__attribute__((address_space(1))) unsigned int*)(g),
      (__attribute__((address_space(3))) unsigned int*)(l), 16, 0, 0);
}

/* ------- kernel 0: f32 -> bf16 convert + zero pad buffer + zero out ------ */
__global__ void k_convert(const float* __restrict__ o, const float* __restrict__ w,
                          u16* __restrict__ obf, u16* __restrict__ wbf,
                          u16* __restrict__ zbuf, float* __restrict__ out) {
  const int stride = gridDim.x * blockDim.x;
  const int tid0 = blockIdx.x * blockDim.x + threadIdx.x;
  const int no8 = NB*TO*DD/8;
  const int nw8 = NB*TW*DD/8;
  for (int i = tid0; i < no8; i += stride) {
    const float4* s = (const float4*)o + (size_t)i*2;
    float4 a = s[0], b = s[1];
    u16x8 r = { f2bf(a.x), f2bf(a.y), f2bf(a.z), f2bf(a.w),
                f2bf(b.x), f2bf(b.y), f2bf(b.z), f2bf(b.w) };
    *(u16x8*)(obf + (size_t)i*8) = r;
  }
  for (int i = tid0; i < nw8; i += stride) {
    const float4* s = (const float4*)w + (size_t)i*2;
    float4 a = s[0], b = s[1];
    u16x8 r = { f2bf(a.x), f2bf(a.y), f2bf(a.z), f2bf(a.w),
                f2bf(b.x), f2bf(b.y), f2bf(b.z), f2bf(b.w) };
    *(u16x8*)(wbf + (size_t)i*8) = r;
  }
  if (tid0 < 16) {
    u16x8 z = {0,0,0,0,0,0,0,0};
    *(u16x8*)(zbuf + tid0*8) = z;
  }
  if (tid0 == 0) out[0] = 0.f;
}

/* ------- kernel 1: fused S=W·O^T GEMM + row softmax-weighted mean -------- */
/* grid: (48 ob-pairs, 30 row-tiles), 256 threads = 4 waves.
   TRIPLE-buffered K-tile pipeline with counted vmcnt (T3/T4 minimum form):
   stage kt t+3 while computing kt t; vmcnt(8) keeps 2 K-tiles of loads in
   flight across barriers (never drains to 0 in steady state).
   Each wave owns a 64x64 tile; its 64 cols = exactly one ob group. */
__global__ void __launch_bounds__(256) k_main(
    const u16* __restrict__ wbf, const u16* __restrict__ obf,
    const u16* __restrict__ zbuf, float* __restrict__ logits) {
  __shared__ u16 ldsA[3][BM*BK];   /* 3 x 8 KB */
  __shared__ u16 ldsB[3][BM*BK];   /* 3 x 8 KB  -> 48 KB total, 3 blocks/CU */
  const int tid  = threadIdx.x;
  const int lane = tid & 63;
  const int wid  = tid >> 6;
  const int r0   = blockIdx.y * BM;
  const int ob0  = blockIdx.x * 2;

  /* staging precompute: 16B chunk c = i*256 + tid; row = c>>2, kchunk = c&3 */
  const u16* gA[2];
  const u16* gB[2];
  bool realB[2];
  #pragma unroll
  for (int i = 0; i < 2; ++i) {
    int c   = i*256 + tid;
    int row = c >> 2;
    int kc8 = (c & 3) * 8;
    gA[i] = wbf + (size_t)(r0 + row) * DD + kc8;
    int ob = ob0 + (row >> 6);
    int oo = row & 63;
    realB[i] = (oo < TO);
    gB[i] = realB[i] ? (obf + ((size_t)ob * TO + oo) * DD + kc8) : zbuf;
  }
  const int ldst = (wid * 64) * 8;  /* wave-uniform LDS chunk base (elems) */

  auto stage = [&](int buf, int k0) {
    #pragma unroll
    for (int i = 0; i < 2; ++i) {
      gload16(gA[i] + k0, &ldsA[buf][i*2048 + ldst]);
      gload16(realB[i] ? gB[i] + k0 : gB[i], &ldsB[buf][i*2048 + ldst]);
    }
  };

  const int wr   = (wid >> 1) * 64;
  const int wc   = (wid & 1) * 64;
  const int lrow = lane & 15;
  const int lk   = (lane >> 4) * 8;

  f32x4 zero4 = {0.f, 0.f, 0.f, 0.f};
  f32x4 acc[4][4];
  #pragma unroll
  for (int mi = 0; mi < 4; ++mi)
    #pragma unroll
    for (int ni = 0; ni < 4; ++ni) acc[mi][ni] = zero4;

  /* prologue: 3 K-tiles in flight (12 loads/thread) */
  stage(0, 0);
  stage(1, BK);
  stage(2, 2*BK);

  int cur = 0;
  for (int kc = 0; kc < NKC; ++kc) {
    /* wait until kt kc's 4 loads (per thread) are drained; keep the rest
       in flight. Tail: kc=NKC-2 -> 4 outstanding-2 tiles; last -> 0. */
    if (kc <= NKC - 3)      asm volatile("s_waitcnt vmcnt(8)" ::: "memory");
    else if (kc == NKC - 2) asm volatile("s_waitcnt vmcnt(4)" ::: "memory");
    else                    asm volatile("s_waitcnt vmcnt(0)" ::: "memory");
    __builtin_amdgcn_s_barrier();     /* all waves' kt-kc loads complete   */

    short8 af[4], bfr[4];
    #pragma unroll
    for (int mi = 0; mi < 4; ++mi)
      af[mi] = *(const short8*)&ldsA[cur][(wr + mi*16 + lrow) * BK + lk];
    #pragma unroll
    for (int ni = 0; ni < 4; ++ni)
      bfr[ni] = *(const short8*)&ldsB[cur][(wc + ni*16 + lrow) * BK + lk];
    #pragma unroll
    for (int mi = 0; mi < 4; ++mi)
      #pragma unroll
      for (int ni = 0; ni < 4; ++ni)
        acc[mi][ni] = __builtin_amdgcn_mfma_f32_16x16x32_bf16(
            af[mi], bfr[ni], acc[mi][ni], 0, 0, 0);

    __builtin_amdgcn_s_barrier();     /* all waves done reading buf[cur]   */
    if (kc + 3 < NKC) stage(cur, (kc + 3) * BK);
    cur = (cur == 2) ? 0 : cur + 1;
  }

  /* epilogue: per row (over this wave's 64 cols = one ob, 50 real):
     logits = sum(p*S_raw)/sum(p), p = exp(scale*(S_raw - max)).
     layout: logits[row][ob], row = wb*TW + t = flat W row. */
  const float scale = 0.04419417382415922f;  /* 1/sqrt(512) */
  const int ob = ob0 + (wid & 1);
  #pragma unroll
  for (int mi = 0; mi < 4; ++mi) {
    #pragma unroll
    for (int q = 0; q < 4; ++q) {
      float v0 = acc[mi][0][q], v1 = acc[mi][1][q],
            v2 = acc[mi][2][q], v3 = acc[mi][3][q];
      /* cols: ni*16+lrow ; ni<3 always real, ni=3 real iff lrow<2 */
      float m = fmaxf(fmaxf(v0, v1), v2);
      if (lrow < 2) m = fmaxf(m, v3);
      #pragma unroll
      for (int d = 1; d < 16; d <<= 1) m = fmaxf(m, __shfl_xor(m, d));
      float p0 = __expf((v0 - m) * scale);
      float p1 = __expf((v1 - m) * scale);
      float p2 = __expf((v2 - m) * scale);
      float den = p0 + p1 + p2;
      float num = p0*v0 + p1*v1 + p2*v2;
      if (lrow < 2) {
        float p3 = __expf((v3 - m) * scale);
        den += p3; num += p3*v3;
      }
      #pragma unroll
      for (int d = 1; d < 16; d <<= 1) {
        den += __shfl_xor(den, d);
        num += __shfl_xor(num, d);
      }
      if (lrow == 0) {
        int row = r0 + wr + mi*16 + (lane >> 4)*4 + q;
        logits[(size_t)row * NB + ob] = num / den;
      }
    }
  }
}

/* ---- kernel 2: 60 blocks x 8 waves; each wave 8 rows; LSE over 96 obs;
       per-block LDS reduce -> ONE atomicAdd per block (60 total) ---------- */
__global__ void __launch_bounds__(512) k_lse(
    const float* __restrict__ logits, float* __restrict__ out) {
  __shared__ float red[8];
  const int tid  = threadIdx.x;
  const int lane = tid & 63;
  const int wid  = tid >> 6;                 /* 0..7 */
  const int gw   = blockIdx.x * 8 + wid;     /* 0..479 */
  float acc = 0.f;
  #pragma unroll
  for (int i = 0; i < 8; ++i) {
    const int row = gw * 8 + i;              /* 480*8 = 3840 rows */
    const float* base = logits + (size_t)row * NB;
    float v0 = base[lane];
    float v1 = (lane < NB - 64) ? base[64 + lane] : -1e30f;
    float m = fmaxf(v0, v1);
    #pragma unroll
    for (int d = 1; d < 64; d <<= 1) m = fmaxf(m, __shfl_xor(m, d));
    float den = __expf(v0 - m) + ((lane < NB - 64) ? __expf(v1 - m) : 0.f);
    #pragma unroll
    for (int d = 1; d < 64; d <<= 1) den += __shfl_xor(den, d);
    if (lane == 0) {
      const int wb = row / TW;               /* diagonal ob index */
      acc += base[wb] - m - __logf(den);
    }
  }
  if (lane == 0) red[wid] = acc;
  __syncthreads();
  if (tid == 0) {
    float s = red[0] + red[1] + red[2] + red[3]
            + red[4] + red[5] + red[6] + red[7];
    atomicAdd(out, s * (-1.0f / (float)MROWS));
  }
}

extern "C" void kernel_launch(void* const* d_in, const int* in_sizes, int n_in,
                              void* d_out, int out_size, void* d_ws, size_t ws_size,
                              hipStream_t stream) {
  const float* o = (const float*)d_in[0];   /* (96,50,512) f32 */
  const float* w = (const float*)d_in[1];   /* (96,40,512) f32 */
  char* ws = (char*)d_ws;
  u16*    wbf     = (u16*)(ws + WBF_OFF);
  u16*    obf     = (u16*)(ws + OBF_OFF);
  float*  logits  = (float*)(ws + LOG_OFF);
  u16*    zbuf    = (u16*)(ws + ZB_OFF);

  k_convert<<<1200, 256, 0, stream>>>(o, w, obf, wbf, zbuf, (float*)d_out);
  dim3 g1(NB/2, MROWS/BM);
  k_main<<<g1, 256, 0, stream>>>(wbf, obf, zbuf, logits);
  k_lse<<<60, 512, 0, stream>>>(logits, (float*)d_out);
}

// Round 7
// 116.404 us; speedup vs baseline: 1.0002x; 1.0002x over previous
//
#include <hip/hip_runtime.h>
#include <cstdint>
#include <cstddef>

typedef unsigned short u16;
typedef __attribute__((ext_vector_type(8))) short short8;
typedef __attribute__((ext_vector_type(8))) unsigned short u16x8;
typedef __attribute__((ext_vector_type(4))) float f32x4;

#define NB   96
#define TO   50
#define TW   40
#define DD   512
#define MROWS (NB*TW)      /* 3840 */
#define BM   128
#define BK   32
#define NKC  (DD/BK)       /* 16 */

/* workspace layout (bytes) */
#define WBF_OFF   0u
#define OBF_OFF   (MROWS*DD*2u)              /* 3,932,160  */
#define LOG_OFF   (OBF_OFF + NB*TO*DD*2u)    /* 8,847,360  */
#define ZB_OFF    (LOG_OFF + MROWS*NB*4u)    /* 10,321,920 */

__device__ __forceinline__ u16 f2bf(float f) {
  unsigned int u = __builtin_bit_cast(unsigned int, f);
  u += 0x7fffu + ((u >> 16) & 1u);           /* RNE */
  return (u16)(u >> 16);
}

__device__ __forceinline__ void gload16(const void* g, void* l) {
  __builtin_amdgcn_global_load_lds(
      (__attribute__((address_space(1))) unsigned int*)(g),
      (__attribute__((address_space(3))) unsigned int*)(l), 16, 0, 0);
}

/* ------- kernel 0: f32 -> bf16 convert + zero pad buffer + zero out ------ */
__global__ void k_convert(const float* __restrict__ o, const float* __restrict__ w,
                          u16* __restrict__ obf, u16* __restrict__ wbf,
                          u16* __restrict__ zbuf, float* __restrict__ out) {
  const int stride = gridDim.x * blockDim.x;
  const int tid0 = blockIdx.x * blockDim.x + threadIdx.x;
  const int no8 = NB*TO*DD/8;
  const int nw8 = NB*TW*DD/8;
  for (int i = tid0; i < no8; i += stride) {
    const float4* s = (const float4*)o + (size_t)i*2;
    float4 a = s[0], b = s[1];
    u16x8 r = { f2bf(a.x), f2bf(a.y), f2bf(a.z), f2bf(a.w),
                f2bf(b.x), f2bf(b.y), f2bf(b.z), f2bf(b.w) };
    *(u16x8*)(obf + (size_t)i*8) = r;
  }
  for (int i = tid0; i < nw8; i += stride) {
    const float4* s = (const float4*)w + (size_t)i*2;
    float4 a = s[0], b = s[1];
    u16x8 r = { f2bf(a.x), f2bf(a.y), f2bf(a.z), f2bf(a.w),
                f2bf(b.x), f2bf(b.y), f2bf(b.z), f2bf(b.w) };
    *(u16x8*)(wbf + (size_t)i*8) = r;
  }
  if (tid0 < 16) {
    u16x8 z = {0,0,0,0,0,0,0,0};
    *(u16x8*)(zbuf + tid0*8) = z;
  }
  if (tid0 == 0) out[0] = 0.f;
}

/* ------- kernel 1: fused S=W·O^T GEMM + row softmax-weighted mean --------
   Round-5 loop structure (2-buffer, single __syncthreads/K-step, 47us
   proven) + LDS bank-conflict swizzle:
     physical_byte = logical_byte ^ (((logical_byte>>7)&7)<<4)
   (bits 4-6 only -> involution). Staging keeps LDS dest LINEAR (m104) and
   pre-permutes the GLOBAL source chunk: c' = c ^ ((c>>3)&7). Reads apply
   the same XOR. Kills the 8-way granule conflict (row-parity pattern). */
__global__ void __launch_bounds__(256) k_main(
    const u16* __restrict__ wbf, const u16* __restrict__ obf,
    const u16* __restrict__ zbuf, float* __restrict__ logits) {
  __shared__ u16 ldsA[2][BM*BK];
  __shared__ u16 ldsB[2][BM*BK];
  const int tid  = threadIdx.x;
  const int lane = tid & 63;
  const int wid  = tid >> 6;
  const int r0   = blockIdx.y * BM;
  const int ob0  = blockIdx.x * 2;

  /* staging precompute: LDS dest chunk c = i*256 + tid (linear); global
     source chunk cs = c ^ ((c>>3)&7)  [swizzle pre-permutation] */
  const u16* gA[2];
  const u16* gB[2];
  bool realB[2];
  #pragma unroll
  for (int i = 0; i < 2; ++i) {
    int c   = i*256 + tid;
    int cs  = c ^ ((c >> 3) & 7);
    int row = cs >> 2;
    int kc8 = (cs & 3) * 8;
    gA[i] = wbf + (size_t)(r0 + row) * DD + kc8;
    int ob = ob0 + (row >> 6);
    int oo = row & 63;
    realB[i] = (oo < TO);
    gB[i] = realB[i] ? (obf + ((size_t)ob * TO + oo) * DD + kc8) : zbuf;
  }
  const int ldst = (wid * 64) * 8;  /* wave-uniform LDS chunk base (elems) */

  auto stage = [&](int buf, int k0) {
    #pragma unroll
    for (int i = 0; i < 2; ++i) {
      gload16(gA[i] + k0, &ldsA[buf][i*2048 + ldst]);
      gload16(realB[i] ? gB[i] + k0 : gB[i], &ldsB[buf][i*2048 + ldst]);
    }
  };

  const int wr   = (wid >> 1) * 64;
  const int wc   = (wid & 1) * 64;
  const int lrow = lane & 15;
  const int lq16 = (lane >> 4) * 16;   /* byte offset of k-quad */

  /* loop-invariant swizzled read offsets (bytes within one tile buffer) */
  int offA[4], offB[4];
  #pragma unroll
  for (int mi = 0; mi < 4; ++mi) {
    int row = wr + mi*16 + lrow;
    int off = row*64 + lq16;
    offA[mi] = off ^ ((((unsigned)off >> 7) & 7) << 4);
  }
  #pragma unroll
  for (int ni = 0; ni < 4; ++ni) {
    int row = wc + ni*16 + lrow;
    int off = row*64 + lq16;
    offB[ni] = off ^ ((((unsigned)off >> 7) & 7) << 4);
  }

  f32x4 zero4 = {0.f, 0.f, 0.f, 0.f};
  f32x4 acc[4][4];
  #pragma unroll
  for (int mi = 0; mi < 4; ++mi)
    #pragma unroll
    for (int ni = 0; ni < 4; ++ni) acc[mi][ni] = zero4;

  stage(0, 0);
  for (int kc = 0; kc < NKC; ++kc) {
    const int cur = kc & 1;
    __syncthreads();                    /* drains vmcnt -> buf[cur] ready */
    if (kc + 1 < NKC) stage(cur ^ 1, (kc + 1) * BK);
    const char* baseA = (const char*)&ldsA[cur][0];
    const char* baseB = (const char*)&ldsB[cur][0];
    short8 af[4], bfr[4];
    #pragma unroll
    for (int mi = 0; mi < 4; ++mi)
      af[mi] = *(const short8*)(baseA + offA[mi]);
    #pragma unroll
    for (int ni = 0; ni < 4; ++ni)
      bfr[ni] = *(const short8*)(baseB + offB[ni]);
    #pragma unroll
    for (int mi = 0; mi < 4; ++mi)
      #pragma unroll
      for (int ni = 0; ni < 4; ++ni)
        acc[mi][ni] = __builtin_amdgcn_mfma_f32_16x16x32_bf16(
            af[mi], bfr[ni], acc[mi][ni], 0, 0, 0);
  }

  /* epilogue: per row (over this wave's 64 cols = one ob, 50 real):
     logits = sum(p*S_raw)/sum(p), p = exp(scale*(S_raw - max)).
     layout: logits[row][ob], row = wb*TW + t = flat W row. */
  const float scale = 0.04419417382415922f;  /* 1/sqrt(512) */
  const int ob = ob0 + (wid & 1);
  #pragma unroll
  for (int mi = 0; mi < 4; ++mi) {
    #pragma unroll
    for (int q = 0; q < 4; ++q) {
      float v0 = acc[mi][0][q], v1 = acc[mi][1][q],
            v2 = acc[mi][2][q], v3 = acc[mi][3][q];
      /* cols: ni*16+lrow ; ni<3 always real, ni=3 real iff lrow<2 */
      float m = fmaxf(fmaxf(v0, v1), v2);
      if (lrow < 2) m = fmaxf(m, v3);
      #pragma unroll
      for (int d = 1; d < 16; d <<= 1) m = fmaxf(m, __shfl_xor(m, d));
      float p0 = __expf((v0 - m) * scale);
      float p1 = __expf((v1 - m) * scale);
      float p2 = __expf((v2 - m) * scale);
      float den = p0 + p1 + p2;
      float num = p0*v0 + p1*v1 + p2*v2;
      if (lrow < 2) {
        float p3 = __expf((v3 - m) * scale);
        den += p3; num += p3*v3;
      }
      #pragma unroll
      for (int d = 1; d < 16; d <<= 1) {
        den += __shfl_xor(den, d);
        num += __shfl_xor(num, d);
      }
      if (lrow == 0) {
        int row = r0 + wr + mi*16 + (lane >> 4)*4 + q;
        logits[(size_t)row * NB + ob] = num / den;
      }
    }
  }
}

/* ---- kernel 2: 60 blocks x 8 waves; each wave 8 rows; LSE over 96 obs;
       per-block LDS reduce -> ONE atomicAdd per block (60 total) ---------- */
__global__ void __launch_bounds__(512) k_lse(
    const float* __restrict__ logits, float* __restrict__ out) {
  __shared__ float red[8];
  const int tid  = threadIdx.x;
  const int lane = tid & 63;
  const int wid  = tid >> 6;                 /* 0..7 */
  const int gw   = blockIdx.x * 8 + wid;     /* 0..479 */
  float acc = 0.f;
  #pragma unroll
  for (int i = 0; i < 8; ++i) {
    const int row = gw * 8 + i;              /* 480*8 = 3840 rows */
    const float* base = logits + (size_t)row * NB;
    float v0 = base[lane];
    float v1 = (lane < NB - 64) ? base[64 + lane] : -1e30f;
    float m = fmaxf(v0, v1);
    #pragma unroll
    for (int d = 1; d < 64; d <<= 1) m = fmaxf(m, __shfl_xor(m, d));
    float den = __expf(v0 - m) + ((lane < NB - 64) ? __expf(v1 - m) : 0.f);
    #pragma unroll
    for (int d = 1; d < 64; d <<= 1) den += __shfl_xor(den, d);
    if (lane == 0) {
      const int wb = row / TW;               /* diagonal ob index */
      acc += base[wb] - m - __logf(den);
    }
  }
  if (lane == 0) red[wid] = acc;
  __syncthreads();
  if (tid == 0) {
    float s = red[0] + red[1] + red[2] + red[3]
            + red[4] + red[5] + red[6] + red[7];
    atomicAdd(out, s * (-1.0f / (float)MROWS));
  }
}

extern "C" void kernel_launch(void* const* d_in, const int* in_sizes, int n_in,
                              void* d_out, int out_size, void* d_ws, size_t ws_size,
                              hipStream_t stream) {
  const float* o = (const float*)d_in[0];   /* (96,50,512) f32 */
  const float* w = (const float*)d_in[1];   /* (96,40,512) f32 */
  char* ws = (char*)d_ws;
  u16*    wbf     = (u16*)(ws + WBF_OFF);
  u16*    obf     = (u16*)(ws + OBF_OFF);
  float*  logits  = (float*)(ws + LOG_OFF);
  u16*    zbuf    = (u16*)(ws + ZB_OFF);

  k_convert<<<1200, 256, 0, stream>>>(o, w, obf, wbf, zbuf, (float*)d_out);
  dim3 g1(NB/2, MROWS/BM);
  k_main<<<g1, 256, 0, stream>>>(wbf, obf, zbuf, logits);
  k_lse<<<60, 512, 0, stream>>>(logits, (float*)d_out);
}

// Round 9
// 116.008 us; speedup vs baseline: 1.0036x; 1.0034x over previous
//
#include <hip/hip_runtime.h>
#include <cstdint>
#include <cstddef>

typedef unsigned short u16;
typedef __attribute__((ext_vector_type(8))) short short8;
typedef __attribute__((ext_vector_type(8))) unsigned short u16x8;
typedef __attribute__((ext_vector_type(4))) float f32x4;

#define NB   96
#define TO   50
#define TW   40
#define DD   512
#define MROWS (NB*TW)      /* 3840 */
#define BM   128
#define BK   32
#define NKC  (DD/BK)       /* 16 */

/* workspace layout (bytes) */
#define WBF_OFF   0u
#define OBF_OFF   (MROWS*DD*2u)              /* 3,932,160  */
#define LOG_OFF   (OBF_OFF + NB*TO*DD*2u)    /* 8,847,360  */
#define ZB_OFF    (LOG_OFF + MROWS*NB*4u)    /* 10,321,920 */

__device__ __forceinline__ u16 f2bf(float f) {
  unsigned int u = __builtin_bit_cast(unsigned int, f);
  u += 0x7fffu + ((u >> 16) & 1u);           /* RNE */
  return (u16)(u >> 16);
}

__device__ __forceinline__ void gload16(const void* g, void* l) {
  __builtin_amdgcn_global_load_lds(
      (__attribute__((address_space(1))) unsigned int*)(g),
      (__attribute__((address_space(3))) unsigned int*)(l), 16, 0, 0);
}

/* ------- kernel 0: f32 -> bf16 convert + zero pad buffer + zero out ------ */
__global__ void k_convert(const float* __restrict__ o, const float* __restrict__ w,
                          u16* __restrict__ obf, u16* __restrict__ wbf,
                          u16* __restrict__ zbuf, float* __restrict__ out) {
  const int stride = gridDim.x * blockDim.x;
  const int tid0 = blockIdx.x * blockDim.x + threadIdx.x;
  const int no8 = NB*TO*DD/8;
  const int nw8 = NB*TW*DD/8;
  for (int i = tid0; i < no8; i += stride) {
    const float4* s = (const float4*)o + (size_t)i*2;
    float4 a = s[0], b = s[1];
    u16x8 r = { f2bf(a.x), f2bf(a.y), f2bf(a.z), f2bf(a.w),
                f2bf(b.x), f2bf(b.y), f2bf(b.z), f2bf(b.w) };
    *(u16x8*)(obf + (size_t)i*8) = r;
  }
  for (int i = tid0; i < nw8; i += stride) {
    const float4* s = (const float4*)w + (size_t)i*2;
    float4 a = s[0], b = s[1];
    u16x8 r = { f2bf(a.x), f2bf(a.y), f2bf(a.z), f2bf(a.w),
                f2bf(b.x), f2bf(b.y), f2bf(b.z), f2bf(b.w) };
    *(u16x8*)(wbf + (size_t)i*8) = r;
  }
  if (tid0 < 16) {
    u16x8 z = {0,0,0,0,0,0,0,0};
    *(u16x8*)(zbuf + tid0*8) = z;
  }
  if (tid0 == 0) out[0] = 0.f;
}

/* ------- kernel 1: fused S=W·O^T GEMM + row softmax-weighted mean --------
   Round-7 body (2-buffer loop + conflict-free swizzled LDS, 46us proven)
   + XCD-partition block swizzle (T1): flat grid 1440; xcd = L&7 owns
   ob-pair band x in [6*xcd, 6*xcd+6) across all 30 row-tiles ->
   per-XCD L2 working set ~4.5MB (B band 0.6MB hot + A streamed)
   instead of 8.8MB scatter-thrash. */
__global__ void __launch_bounds__(256) k_main(
    const u16* __restrict__ wbf, const u16* __restrict__ obf,
    const u16* __restrict__ zbuf, float* __restrict__ logits) {
  __shared__ u16 ldsA[2][BM*BK];
  __shared__ u16 ldsB[2][BM*BK];
  const int tid  = threadIdx.x;
  const int lane = tid & 63;
  const int wid  = tid >> 6;

  /* XCD-aware decode: HW round-robins linear id over 8 XCDs */
  const int L   = blockIdx.x;          /* 0..1439 */
  const int xcd = L & 7;
  const int idx = L >> 3;              /* 0..179  */
  const int xb  = xcd * 6 + (idx % 6); /* ob-pair 0..47 : banded per XCD */
  const int yb  = idx / 6;             /* row-tile 0..29 */
  const int r0   = yb * BM;
  const int ob0  = xb * 2;

  /* staging precompute: LDS dest chunk c = i*256 + tid (linear); global
     source chunk cs = c ^ ((c>>3)&7)  [swizzle pre-permutation] */
  const u16* gA[2];
  const u16* gB[2];
  bool realB[2];
  #pragma unroll
  for (int i = 0; i < 2; ++i) {
    int c   = i*256 + tid;
    int cs  = c ^ ((c >> 3) & 7);
    int row = cs >> 2;
    int kc8 = (cs & 3) * 8;
    gA[i] = wbf + (size_t)(r0 + row) * DD + kc8;
    int ob = ob0 + (row >> 6);
    int oo = row & 63;
    realB[i] = (oo < TO);
    gB[i] = realB[i] ? (obf + ((size_t)ob * TO + oo) * DD + kc8) : zbuf;
  }
  const int ldst = (wid * 64) * 8;  /* wave-uniform LDS chunk base (elems) */

  auto stage = [&](int buf, int k0) {
    #pragma unroll
    for (int i = 0; i < 2; ++i) {
      gload16(gA[i] + k0, &ldsA[buf][i*2048 + ldst]);
      gload16(realB[i] ? gB[i] + k0 : gB[i], &ldsB[buf][i*2048 + ldst]);
    }
  };

  const int wr   = (wid >> 1) * 64;
  const int wc   = (wid & 1) * 64;
  const int lrow = lane & 15;
  const int lq16 = (lane >> 4) * 16;   /* byte offset of k-quad */

  /* loop-invariant swizzled read offsets (bytes within one tile buffer) */
  int offA[4], offB[4];
  #pragma unroll
  for (int mi = 0; mi < 4; ++mi) {
    int row = wr + mi*16 + lrow;
    int off = row*64 + lq16;
    offA[mi] = off ^ ((((unsigned)off >> 7) & 7) << 4);
  }
  #pragma unroll
  for (int ni = 0; ni < 4; ++ni) {
    int row = wc + ni*16 + lrow;
    int off = row*64 + lq16;
    offB[ni] = off ^ ((((unsigned)off >> 7) & 7) << 4);
  }

  f32x4 zero4 = {0.f, 0.f, 0.f, 0.f};
  f32x4 acc[4][4];
  #pragma unroll
  for (int mi = 0; mi < 4; ++mi)
    #pragma unroll
    for (int ni = 0; ni < 4; ++ni) acc[mi][ni] = zero4;

  stage(0, 0);
  for (int kc = 0; kc < NKC; ++kc) {
    const int cur = kc & 1;
    __syncthreads();                    /* drains vmcnt -> buf[cur] ready */
    if (kc + 1 < NKC) stage(cur ^ 1, (kc + 1) * BK);
    const char* baseA = (const char*)&ldsA[cur][0];
    const char* baseB = (const char*)&ldsB[cur][0];
    short8 af[4], bfr[4];
    #pragma unroll
    for (int mi = 0; mi < 4; ++mi)
      af[mi] = *(const short8*)(baseA + offA[mi]);
    #pragma unroll
    for (int ni = 0; ni < 4; ++ni)
      bfr[ni] = *(const short8*)(baseB + offB[ni]);
    #pragma unroll
    for (int mi = 0; mi < 4; ++mi)
      #pragma unroll
      for (int ni = 0; ni < 4; ++ni)
        acc[mi][ni] = __builtin_amdgcn_mfma_f32_16x16x32_bf16(
            af[mi], bfr[ni], acc[mi][ni], 0, 0, 0);
  }

  /* epilogue: per row (over this wave's 64 cols = one ob, 50 real):
     logits = sum(p*S_raw)/sum(p), p = exp(scale*(S_raw - max)).
     layout: logits[row][ob], row = wb*TW + t = flat W row. */
  const float scale = 0.04419417382415922f;  /* 1/sqrt(512) */
  const int ob = ob0 + (wid & 1);
  #pragma unroll
  for (int mi = 0; mi < 4; ++mi) {
    #pragma unroll
    for (int q = 0; q < 4; ++q) {
      float v0 = acc[mi][0][q], v1 = acc[mi][1][q],
            v2 = acc[mi][2][q], v3 = acc[mi][3][q];
      /* cols: ni*16+lrow ; ni<3 always real, ni=3 real iff lrow<2 */
      float m = fmaxf(fmaxf(v0, v1), v2);
      if (lrow < 2) m = fmaxf(m, v3);
      #pragma unroll
      for (int d = 1; d < 16; d <<= 1) m = fmaxf(m, __shfl_xor(m, d));
      float p0 = __expf((v0 - m) * scale);
      float p1 = __expf((v1 - m) * scale);
      float p2 = __expf((v2 - m) * scale);
      float den = p0 + p1 + p2;
      float num = p0*v0 + p1*v1 + p2*v2;
      if (lrow < 2) {
        float p3 = __expf((v3 - m) * scale);
        den += p3; num += p3*v3;
      }
      #pragma unroll
      for (int d = 1; d < 16; d <<= 1) {
        den += __shfl_xor(den, d);
        num += __shfl_xor(num, d);
      }
      if (lrow == 0) {
        int row = r0 + wr + mi*16 + (lane >> 4)*4 + q;
        logits[(size_t)row * NB + ob] = num / den;
      }
    }
  }
}

/* ---- kernel 2: 60 blocks x 8 waves; each wave 8 rows; LSE over 96 obs;
       per-block LDS reduce -> ONE atomicAdd per block (60 total) ---------- */
__global__ void __launch_bounds__(512) k_lse(
    const float* __restrict__ logits, float* __restrict__ out) {
  __shared__ float red[8];
  const int tid  = threadIdx.x;
  const int lane = tid & 63;
  const int wid  = tid >> 6;                 /* 0..7 */
  const int gw   = blockIdx.x * 8 + wid;     /* 0..479 */
  float acc = 0.f;
  #pragma unroll
  for (int i = 0; i < 8; ++i) {
    const int row = gw * 8 + i;              /* 480*8 = 3840 rows */
    const float* base = logits + (size_t)row * NB;
    float v0 = base[lane];
    float v1 = (lane < NB - 64) ? base[64 + lane] : -1e30f;
    float m = fmaxf(v0, v1);
    #pragma unroll
    for (int d = 1; d < 64; d <<= 1) m = fmaxf(m, __shfl_xor(m, d));
    float den = __expf(v0 - m) + ((lane < NB - 64) ? __expf(v1 - m) : 0.f);
    #pragma unroll
    for (int d = 1; d < 64; d <<= 1) den += __shfl_xor(den, d);
    if (lane == 0) {
      const int wb = row / TW;               /* diagonal ob index */
      acc += base[wb] - m - __logf(den);
    }
  }
  if (lane == 0) red[wid] = acc;
  __syncthreads();
  if (tid == 0) {
    float s = red[0] + red[1] + red[2] + red[3]
            + red[4] + red[5] + red[6] + red[7];
    atomicAdd(out, s * (-1.0f / (float)MROWS));
  }
}

extern "C" void kernel_launch(void* const* d_in, const int* in_sizes, int n_in,
                              void* d_out, int out_size, void* d_ws, size_t ws_size,
                              hipStream_t stream) {
  const float* o = (const float*)d_in[0];   /* (96,50,512) f32 */
  const float* w = (const float*)d_in[1];   /* (96,40,512) f32 */
  char* ws = (char*)d_ws;
  u16*    wbf     = (u16*)(ws + WBF_OFF);
  u16*    obf     = (u16*)(ws + OBF_OFF);
  float*  logits  = (float*)(ws + LOG_OFF);
  u16*    zbuf    = (u16*)(ws + ZB_OFF);

  k_convert<<<1200, 256, 0, stream>>>(o, w, obf, wbf, zbuf, (float*)d_out);
  k_main<<<1440, 256, 0, stream>>>(wbf, obf, zbuf, logits);
  k_lse<<<60, 512, 0, stream>>>(logits, (float*)d_out);
}